// Round 4
// baseline (3583.678 us; speedup 1.0000x reference)
//
#include <hip/hip_runtime.h>

#define N_USERS 100000
#define N_ITEMS 50000
#define N_NODES 150000
#define DIM 64
#define NNZ_C 2400000
#define BATCH 16384

#define BROWS 128                      // rows per bucket
#define NBUCK ((N_NODES + BROWS - 1) / BROWS)   // 1172
#define CHUNK 16384                    // edges per build block
#define NCHUNK ((NNZ_C + CHUNK - 1) / CHUNK)    // 147

// ---- k1: per-chunk LDS histogram over buckets (no global atomics) --------
__global__ void k1_hist(const int* __restrict__ rows, int* __restrict__ ghist) {
    __shared__ int hist[NBUCK];
    int blk = blockIdx.x, tid = threadIdx.x;
    for (int b = tid; b < NBUCK; b += 256) hist[b] = 0;
    __syncthreads();
    int base = blk * CHUNK;
    int end = min(base + CHUNK, NNZ_C);
    for (int e = base + tid; e < end; e += 256)
        atomicAdd(&hist[rows[e] >> 7], 1);          // LDS atomic
    __syncthreads();
    for (int b = tid; b < NBUCK; b += 256)
        ghist[(size_t)b * NCHUNK + blk] = hist[b];
}

// ---- k2a: per-bucket exclusive scan over its NCHUNK entries (in place) ---
__global__ void k2a_scan_chunks(int* __restrict__ ghist, int* __restrict__ btot) {
    __shared__ int s[256];
    int b = blockIdx.x, t = threadIdx.x;
    int v = (t < NCHUNK) ? ghist[(size_t)b * NCHUNK + t] : 0;
    s[t] = v;
    __syncthreads();
    for (int off = 1; off < 256; off <<= 1) {
        int u = (t >= off) ? s[t - off] : 0;
        __syncthreads();
        s[t] += u;
        __syncthreads();
    }
    if (t < NCHUNK) ghist[(size_t)b * NCHUNK + t] = s[t] - v;   // exclusive
    if (t == NCHUNK - 1) btot[b] = s[t];                        // bucket total
}

// ---- k2b: exclusive scan of 1172 bucket totals (1 block, 2/thread) -------
__global__ void k2b_scan_buckets(const int* __restrict__ btot, int* __restrict__ bbase) {
    __shared__ int s[1024];
    int t = threadIdx.x;
    int i0 = 2 * t, i1 = 2 * t + 1;
    int v0 = (i0 < NBUCK) ? btot[i0] : 0;
    int v1 = (i1 < NBUCK) ? btot[i1] : 0;
    int pair = v0 + v1;
    s[t] = pair;
    __syncthreads();
    for (int off = 1; off < 1024; off <<= 1) {
        int u = (t >= off) ? s[t - off] : 0;
        __syncthreads();
        s[t] += u;
        __syncthreads();
    }
    int exclP = s[t] - pair;
    if (i0 < NBUCK) bbase[i0] = exclP;
    if (i1 < NBUCK) bbase[i1] = exclP + v0;
    if (t == 1023) bbase[NBUCK] = s[1023];   // == NNZ
}

// ---- k3: scatter edges into bucket-grouped order (LDS cursors only) ------
__global__ void k3_scatter(const int* __restrict__ rows, const int* __restrict__ cols,
                           const float* __restrict__ vals,
                           const int* __restrict__ ghist, const int* __restrict__ bbase,
                           int2* __restrict__ colval, unsigned char* __restrict__ rlbuf) {
    __shared__ int cur[NBUCK];
    int blk = blockIdx.x, tid = threadIdx.x;
    for (int b = tid; b < NBUCK; b += 256)
        cur[b] = bbase[b] + ghist[(size_t)b * NCHUNK + blk];
    __syncthreads();
    int base = blk * CHUNK;
    int end = min(base + CHUNK, NNZ_C);
    for (int e = base + tid; e < end; e += 256) {
        int r = rows[e];
        int pos = atomicAdd(&cur[r >> 7], 1);        // LDS atomic
        int2 cv;
        cv.x = cols[e];
        cv.y = __float_as_int(vals[e]);
        colval[pos] = cv;
        rlbuf[pos] = (unsigned char)(r & 127);
    }
}

// ---- SpMM: one block per bucket, 32KB LDS accumulator tile ---------------
__global__ void spmm_bucket(const int* __restrict__ bbase,
                            const int2* __restrict__ colval,
                            const unsigned char* __restrict__ rlbuf,
                            const float* __restrict__ E, float* __restrict__ Eout) {
    __shared__ float acc[BROWS * DIM];               // 32 KB
    int b = blockIdx.x, tid = threadIdx.x;
    for (int i = tid; i < BROWS * DIM; i += 256) acc[i] = 0.f;
    __syncthreads();
    int start = bbase[b];
    int end = bbase[b + 1];
    int wid = tid >> 6, lane = tid & 63;
    for (int j = start + wid; j < end; j += 4) {
        int ju = __builtin_amdgcn_readfirstlane(j);
        int2 cv = colval[ju];
        int rl = rlbuf[ju];
        float x = __int_as_float(cv.y) * E[(size_t)cv.x * DIM + lane];
        __hip_atomic_fetch_add(&acc[rl * DIM + lane], x,
                               __ATOMIC_RELAXED, __HIP_MEMORY_SCOPE_WORKGROUP);
    }
    __syncthreads();
    int rowbase = b * BROWS;
    int nrows = min(BROWS, N_NODES - rowbase);
    float* dst = Eout + (size_t)rowbase * DIM;
    for (int i = tid; i < nrows * DIM; i += 256) dst[i] = acc[i];
}

// ---- batch init / accumulate ---------------------------------------------
__global__ void batch_init(const float* __restrict__ E, const int* __restrict__ U,
                           const int* __restrict__ I,
                           float* __restrict__ accU, float* __restrict__ accI) {
    int t = blockIdx.x * blockDim.x + threadIdx.x;
    int b = t >> 6, lane = t & 63;
    if (b >= BATCH) return;
    int bu = __builtin_amdgcn_readfirstlane(b);
    int u = U[bu], it = I[bu];
    accU[(size_t)b * DIM + lane] = E[(size_t)u * DIM + lane];
    accI[(size_t)b * DIM + lane] = E[(size_t)(N_USERS + it) * DIM + lane];
}

__global__ void batch_acc(const float* __restrict__ E, const int* __restrict__ U,
                          const int* __restrict__ I,
                          float* __restrict__ accU, float* __restrict__ accI) {
    int t = blockIdx.x * blockDim.x + threadIdx.x;
    int b = t >> 6, lane = t & 63;
    if (b >= BATCH) return;
    int bu = __builtin_amdgcn_readfirstlane(b);
    int u = U[bu], it = I[bu];
    accU[(size_t)b * DIM + lane] += E[(size_t)u * DIM + lane];
    accI[(size_t)b * DIM + lane] += E[(size_t)(N_USERS + it) * DIM + lane];
}

// ---- fused final: add layer-3 rows and dot, scale 1/16 -------------------
__global__ void dot_fused(const float* __restrict__ E3, const int* __restrict__ U,
                          const int* __restrict__ I,
                          const float* __restrict__ accU, const float* __restrict__ accI,
                          float* __restrict__ out) {
    int t = blockIdx.x * blockDim.x + threadIdx.x;
    int b = t >> 6, lane = t & 63;
    if (b >= BATCH) return;
    int bu = __builtin_amdgcn_readfirstlane(b);
    int u = U[bu], it = I[bu];
    float su = accU[(size_t)b * DIM + lane] + E3[(size_t)u * DIM + lane];
    float si = accI[(size_t)b * DIM + lane] + E3[(size_t)(N_USERS + it) * DIM + lane];
    float p = su * si;
    #pragma unroll
    for (int off = 32; off; off >>= 1) p += __shfl_xor(p, off, 64);
    if (lane == 0) out[b] = p * (1.0f / 16.0f);
}

extern "C" void kernel_launch(void* const* d_in, const int* in_sizes, int n_in,
                              void* d_out, int out_size, void* d_ws, size_t ws_size,
                              hipStream_t stream) {
    const float* emb   = (const float*)d_in[0];
    const int*   Arows = (const int*)d_in[1];
    const int*   Acols = (const int*)d_in[2];
    const float* Avals = (const float*)d_in[3];
    const int*   U     = (const int*)d_in[4];
    const int*   I     = (const int*)d_in[5];
    float* out = (float*)d_out;

    char* ws = (char*)d_ws;
    size_t off = 0;
    auto alloc = [&](size_t bytes) {
        char* p = ws + off;
        off += (bytes + 255) & ~(size_t)255;
        return p;
    };
    float*         e0     = (float*)alloc((size_t)N_NODES * DIM * 4);   // 38.4 MB
    float*         e1     = (float*)alloc((size_t)N_NODES * DIM * 4);   // 38.4 MB
    int2*          colval = (int2*) alloc(((size_t)NNZ_C + 64) * 8);    // 19.2 MB
    unsigned char* rlbuf  = (unsigned char*)alloc((size_t)NNZ_C + 64);  // 2.4 MB
    float*         accU   = (float*)alloc((size_t)BATCH * DIM * 4);     // 4.2 MB
    float*         accI   = (float*)alloc((size_t)BATCH * DIM * 4);     // 4.2 MB
    int*           ghist  = (int*)  alloc((size_t)NBUCK * NCHUNK * 4);  // 0.7 MB
    int*           btot   = (int*)  alloc((size_t)NBUCK * 4);
    int*           bbase  = (int*)  alloc((size_t)(NBUCK + 1) * 4);

    // ---- build bucket-grouped edge list (no global atomics) ----
    k1_hist<<<NCHUNK, 256, 0, stream>>>(Arows, ghist);
    k2a_scan_chunks<<<NBUCK, 256, 0, stream>>>(ghist, btot);
    k2b_scan_buckets<<<1, 1024, 0, stream>>>(btot, bbase);
    k3_scatter<<<NCHUNK, 256, 0, stream>>>(Arows, Acols, Avals, ghist, bbase, colval, rlbuf);

    int bacc_blocks = (BATCH * 64 + 255) / 256;

    // layer 0
    batch_init<<<bacc_blocks, 256, 0, stream>>>(emb, U, I, accU, accI);
    // layer 1: emb -> e0
    spmm_bucket<<<NBUCK, 256, 0, stream>>>(bbase, colval, rlbuf, emb, e0);
    batch_acc<<<bacc_blocks, 256, 0, stream>>>(e0, U, I, accU, accI);
    // layer 2: e0 -> e1
    spmm_bucket<<<NBUCK, 256, 0, stream>>>(bbase, colval, rlbuf, e0, e1);
    batch_acc<<<bacc_blocks, 256, 0, stream>>>(e1, U, I, accU, accI);
    // layer 3: e1 -> e0, fused with final dot
    spmm_bucket<<<NBUCK, 256, 0, stream>>>(bbase, colval, rlbuf, e1, e0);
    dot_fused<<<bacc_blocks, 256, 0, stream>>>(e0, U, I, accU, accI, out);
}

// Round 6
// 342.469 us; speedup vs baseline: 10.4643x; 10.4643x over previous
//
#include <hip/hip_runtime.h>

#define N_USERS 100000
#define N_ITEMS 50000
#define N_NODES 150000
#define DIM 64
#define NNZ_C 2400000
#define BATCH 16384

#define BROWS 128
#define NBUCK ((N_NODES + BROWS - 1) / BROWS)     // 1172
#define CHUNK 16384
#define NCHUNK ((NNZ_C + CHUNK - 1) / CHUNK)      // 147

typedef float f32x4 __attribute__((ext_vector_type(4)));

// ---- k1: per-chunk LDS histogram over buckets ----------------------------
__global__ void k1_hist(const int* __restrict__ rows, int* __restrict__ ghist) {
    __shared__ int hist[NBUCK];
    int blk = blockIdx.x, tid = threadIdx.x;
    for (int b = tid; b < NBUCK; b += 256) hist[b] = 0;
    __syncthreads();
    int base = blk * CHUNK;
    int end = min(base + CHUNK, NNZ_C);
    for (int e = base + tid; e < end; e += 256)
        atomicAdd(&hist[rows[e] >> 7], 1);        // LDS atomic
    __syncthreads();
    for (int b = tid; b < NBUCK; b += 256)
        ghist[(size_t)b * NCHUNK + blk] = hist[b];
}

// ---- k2a: per-bucket exclusive scan over NCHUNK entries ------------------
__global__ void k2a_scan_chunks(int* __restrict__ ghist, int* __restrict__ btot) {
    __shared__ int s[256];
    int b = blockIdx.x, t = threadIdx.x;
    int v = (t < NCHUNK) ? ghist[(size_t)b * NCHUNK + t] : 0;
    s[t] = v;
    __syncthreads();
    for (int off = 1; off < 256; off <<= 1) {
        int u = (t >= off) ? s[t - off] : 0;
        __syncthreads();
        s[t] += u;
        __syncthreads();
    }
    if (t < NCHUNK) ghist[(size_t)b * NCHUNK + t] = s[t] - v;
    if (t == NCHUNK - 1) btot[b] = s[t];
}

// ---- k2b: exclusive scan of bucket totals (1 block, 2/thread) ------------
__global__ void k2b_scan_buckets(const int* __restrict__ btot, int* __restrict__ bbase,
                                 int* __restrict__ rowptr) {
    __shared__ int s[1024];
    int t = threadIdx.x;
    int i0 = 2 * t, i1 = 2 * t + 1;
    int v0 = (i0 < NBUCK) ? btot[i0] : 0;
    int v1 = (i1 < NBUCK) ? btot[i1] : 0;
    int pair = v0 + v1;
    s[t] = pair;
    __syncthreads();
    for (int off = 1; off < 1024; off <<= 1) {
        int u = (t >= off) ? s[t - off] : 0;
        __syncthreads();
        s[t] += u;
        __syncthreads();
    }
    int exclP = s[t] - pair;
    if (i0 < NBUCK) bbase[i0] = exclP;
    if (i1 < NBUCK) bbase[i1] = exclP + v0;
    if (t == 1023) { bbase[NBUCK] = s[1023]; rowptr[N_NODES] = NNZ_C; }
}

// ---- k3: scatter edges into bucket-grouped order (LDS cursors) -----------
__global__ void k3_scatter(const int* __restrict__ rows, const int* __restrict__ cols,
                           const float* __restrict__ vals,
                           const int* __restrict__ ghist, const int* __restrict__ bbase,
                           int2* __restrict__ cv_tmp, unsigned char* __restrict__ rl_tmp) {
    __shared__ int cur[NBUCK];
    int blk = blockIdx.x, tid = threadIdx.x;
    for (int b = tid; b < NBUCK; b += 256)
        cur[b] = bbase[b] + ghist[(size_t)b * NCHUNK + blk];
    __syncthreads();
    int base = blk * CHUNK;
    int end = min(base + CHUNK, NNZ_C);
    for (int e = base + tid; e < end; e += 256) {
        int r = rows[e];
        int pos = atomicAdd(&cur[r >> 7], 1);     // LDS atomic
        int2 cv;
        cv.x = cols[e];
        cv.y = __float_as_int(vals[e]);
        cv_tmp[pos] = cv;
        rl_tmp[pos] = (unsigned char)(r & 127);
    }
}

// ---- k4: within-bucket row sort -> rowptr + row-grouped colval -----------
__global__ void k4_sort(const int* __restrict__ bbase,
                        const int2* __restrict__ cv_in,
                        const unsigned char* __restrict__ rl_in,
                        int* __restrict__ rowptr, int2* __restrict__ cv_out) {
    __shared__ int hist[BROWS], scn[BROWS], cur[BROWS];
    int b = blockIdx.x, tid = threadIdx.x;
    int base = bbase[b];
    int cnt = bbase[b + 1] - base;
    if (tid < BROWS) hist[tid] = 0;
    __syncthreads();
    for (int i = tid; i < cnt; i += 256)
        atomicAdd(&hist[rl_in[base + i]], 1);
    __syncthreads();
    if (tid < BROWS) scn[tid] = hist[tid];
    __syncthreads();
    for (int off = 1; off < BROWS; off <<= 1) {
        int u = (tid >= off && tid < BROWS) ? scn[tid - off] : 0;
        __syncthreads();
        if (tid < BROWS) scn[tid] += u;
        __syncthreads();
    }
    if (tid < BROWS) {
        int excl = scn[tid] - hist[tid];
        int g = b * BROWS + tid;
        if (g < N_NODES) rowptr[g] = base + excl;
        cur[tid] = excl;
    }
    __syncthreads();
    for (int i = tid; i < cnt; i += 256) {
        int rl = rl_in[base + i];
        int pos = atomicAdd(&cur[rl], 1);
        cv_out[base + pos] = cv_in[base + i];
    }
}

// ---- SpMM: one wave per row; 16 lanes x float4, 4 edges in flight --------
__global__ void spmm_rows(const int* __restrict__ rowptr, const int2* __restrict__ cv,
                          const float* __restrict__ E, float* __restrict__ Eout) {
    int t = blockIdx.x * blockDim.x + threadIdx.x;
    int row = t >> 6;
    if (row >= N_NODES) return;
    int lane = t & 63;
    int g = lane >> 4, q = lane & 15;
    int ru = __builtin_amdgcn_readfirstlane(row);
    int start = rowptr[ru], end = rowptr[ru + 1];
    float ax = 0.f, ay = 0.f, az = 0.f, aw = 0.f;
    for (int j = start; j < end; j += 4) {
        int jj = j + g;
        int2 c = cv[jj];                          // buffer padded past NNZ
        bool ok = jj < end;
        float v = ok ? __int_as_float(c.y) : 0.f;
        int col = ok ? c.x : 0;
        float4 x = ((const float4*)(E + (size_t)col * DIM))[q];
        ax += v * x.x; ay += v * x.y; az += v * x.z; aw += v * x.w;
    }
    ax += __shfl_xor(ax, 16, 64); ay += __shfl_xor(ay, 16, 64);
    az += __shfl_xor(az, 16, 64); aw += __shfl_xor(aw, 16, 64);
    ax += __shfl_xor(ax, 32, 64); ay += __shfl_xor(ay, 32, 64);
    az += __shfl_xor(az, 32, 64); aw += __shfl_xor(aw, 32, 64);
    if (g == 0) {
        f32x4 o;
        o.x = ax; o.y = ay; o.z = az; o.w = aw;
        __builtin_nontemporal_store(o, (f32x4*)(Eout + (size_t)row * DIM) + q);
    }
}

// ---- batch init / accumulate ---------------------------------------------
__global__ void batch_init(const float* __restrict__ E, const int* __restrict__ U,
                           const int* __restrict__ I,
                           float* __restrict__ accU, float* __restrict__ accI) {
    int t = blockIdx.x * blockDim.x + threadIdx.x;
    int b = t >> 6, lane = t & 63;
    if (b >= BATCH) return;
    int bu = __builtin_amdgcn_readfirstlane(b);
    int u = U[bu], it = I[bu];
    accU[(size_t)b * DIM + lane] = E[(size_t)u * DIM + lane];
    accI[(size_t)b * DIM + lane] = E[(size_t)(N_USERS + it) * DIM + lane];
}

__global__ void batch_acc(const float* __restrict__ E, const int* __restrict__ U,
                          const int* __restrict__ I,
                          float* __restrict__ accU, float* __restrict__ accI) {
    int t = blockIdx.x * blockDim.x + threadIdx.x;
    int b = t >> 6, lane = t & 63;
    if (b >= BATCH) return;
    int bu = __builtin_amdgcn_readfirstlane(b);
    int u = U[bu], it = I[bu];
    accU[(size_t)b * DIM + lane] += E[(size_t)u * DIM + lane];
    accI[(size_t)b * DIM + lane] += E[(size_t)(N_USERS + it) * DIM + lane];
}

// ---- partial layer-3: compute A*E rows only for batch nodes --------------
__global__ void partial3(const int* __restrict__ rowptr, const int2* __restrict__ cv,
                         const float* __restrict__ E,
                         const int* __restrict__ U, const int* __restrict__ I,
                         float* __restrict__ accU, float* __restrict__ accI) {
    int t = blockIdx.x * blockDim.x + threadIdx.x;
    int s = t >> 6;
    if (s >= 2 * BATCH) return;
    int lane = t & 63;
    int g = lane >> 4, q = lane & 15;
    int su = __builtin_amdgcn_readfirstlane(s);
    int row;
    float* acc;
    if (su < BATCH) {
        row = U[su];
        acc = accU + (size_t)su * DIM;
    } else {
        row = N_USERS + I[su - BATCH];
        acc = accI + (size_t)(su - BATCH) * DIM;
    }
    int start = rowptr[row], end = rowptr[row + 1];
    float ax = 0.f, ay = 0.f, az = 0.f, aw = 0.f;
    for (int j = start; j < end; j += 4) {
        int jj = j + g;
        int2 c = cv[jj];
        bool ok = jj < end;
        float v = ok ? __int_as_float(c.y) : 0.f;
        int col = ok ? c.x : 0;
        float4 x = ((const float4*)(E + (size_t)col * DIM))[q];
        ax += v * x.x; ay += v * x.y; az += v * x.z; aw += v * x.w;
    }
    ax += __shfl_xor(ax, 16, 64); ay += __shfl_xor(ay, 16, 64);
    az += __shfl_xor(az, 16, 64); aw += __shfl_xor(aw, 16, 64);
    ax += __shfl_xor(ax, 32, 64); ay += __shfl_xor(ay, 32, 64);
    az += __shfl_xor(az, 32, 64); aw += __shfl_xor(aw, 32, 64);
    if (g == 0) {
        float4 p = ((float4*)acc)[q];
        p.x += ax; p.y += ay; p.z += az; p.w += aw;
        ((float4*)acc)[q] = p;
    }
}

// ---- final dot, scale 1/16 -----------------------------------------------
__global__ void dot_out(const float* __restrict__ accU, const float* __restrict__ accI,
                        float* __restrict__ out) {
    int t = blockIdx.x * blockDim.x + threadIdx.x;
    int b = t >> 6, lane = t & 63;
    if (b >= BATCH) return;
    float p = accU[(size_t)b * DIM + lane] * accI[(size_t)b * DIM + lane];
    #pragma unroll
    for (int off = 32; off; off >>= 1) p += __shfl_xor(p, off, 64);
    if (lane == 0) out[b] = p * (1.0f / 16.0f);
}

extern "C" void kernel_launch(void* const* d_in, const int* in_sizes, int n_in,
                              void* d_out, int out_size, void* d_ws, size_t ws_size,
                              hipStream_t stream) {
    const float* emb   = (const float*)d_in[0];
    const int*   Arows = (const int*)d_in[1];
    const int*   Acols = (const int*)d_in[2];
    const float* Avals = (const float*)d_in[3];
    const int*   U     = (const int*)d_in[4];
    const int*   I     = (const int*)d_in[5];
    float* out = (float*)d_out;

    char* ws = (char*)d_ws;
    size_t off = 0;
    auto alloc = [&](size_t bytes) {
        char* p = ws + off;
        off += (bytes + 255) & ~(size_t)255;
        return p;
    };
    float* e0     = (float*)alloc((size_t)N_NODES * DIM * 4);      // 38.4 MB
    float* e1     = (float*)alloc((size_t)N_NODES * DIM * 4);      // 38.4 MB
    int2*  colval = (int2*) alloc(((size_t)NNZ_C + 64) * 8);       // 19.2 MB (row-sorted)
    float* accU   = (float*)alloc((size_t)BATCH * DIM * 4);        // 4.2 MB
    float* accI   = (float*)alloc((size_t)BATCH * DIM * 4);        // 4.2 MB
    int*   rowptr = (int*)  alloc((size_t)(N_NODES + 1) * 4);      // 0.6 MB

    // Build temporaries aliased into e0/e1 (dead before the layers write them)
    int2*          cv_tmp = (int2*)e0;                             // 19.2 MB in e0
    char*          e1c    = (char*)e1;
    unsigned char* rl_tmp = (unsigned char*)e1c;                   // 2.4 MB
    int*           ghist  = (int*)(e1c + ((NNZ_C + 255) & ~255));  // 0.69 MB
    int*           btot   = ghist + (size_t)NBUCK * NCHUNK;
    int*           bbase  = btot + NBUCK;                          // NBUCK+1 ints

    // ---- build: chunk histogram -> scans -> bucket scatter -> row sort ----
    k1_hist<<<NCHUNK, 256, 0, stream>>>(Arows, ghist);
    k2a_scan_chunks<<<NBUCK, 256, 0, stream>>>(ghist, btot);
    k2b_scan_buckets<<<1, 1024, 0, stream>>>(btot, bbase, rowptr);
    k3_scatter<<<NCHUNK, 256, 0, stream>>>(Arows, Acols, Avals, ghist, bbase,
                                           cv_tmp, rl_tmp);
    k4_sort<<<NBUCK, 256, 0, stream>>>(bbase, cv_tmp, rl_tmp, rowptr, colval);

    int spmm_blocks = (N_NODES * 64 + 255) / 256;
    int bacc_blocks = (BATCH * 64 + 255) / 256;
    int p3_blocks   = (2 * BATCH * 64 + 255) / 256;

    // layer 0
    batch_init<<<bacc_blocks, 256, 0, stream>>>(emb, U, I, accU, accI);
    // layer 1: emb -> e0 (cv_tmp dead from here on)
    spmm_rows<<<spmm_blocks, 256, 0, stream>>>(rowptr, colval, emb, e0);
    batch_acc<<<bacc_blocks, 256, 0, stream>>>(e0, U, I, accU, accI);
    // layer 2: e0 -> e1 (rl_tmp/ghist/btot/bbase dead from here on)
    spmm_rows<<<spmm_blocks, 256, 0, stream>>>(rowptr, colval, e0, e1);
    batch_acc<<<bacc_blocks, 256, 0, stream>>>(e1, U, I, accU, accI);
    // layer 3: only the 2*BATCH rows the output needs
    partial3<<<p3_blocks, 256, 0, stream>>>(rowptr, colval, e1, U, I, accU, accI);
    dot_out<<<bacc_blocks, 256, 0, stream>>>(accU, accI, out);
}